// Round 13
// baseline (597.955 us; speedup 1.0000x reference)
//
#include <hip/hip_runtime.h>
#include <hip/hip_bf16.h>
#include <cstdint>

#define DEVINL __device__ __forceinline__

typedef __attribute__((ext_vector_type(8))) short bf16x8;
typedef __attribute__((ext_vector_type(4))) float f32x4;

DEVINL unsigned short f2bf(float f) {
    union { float f; unsigned u; } v; v.f = f;
    unsigned r = v.u + 0x7fffu + ((v.u >> 16) & 1u);   // RNE
    return (unsigned short)(r >> 16);
}
DEVINL float bf2f(unsigned short h) {
    union { unsigned u; float f; } v; v.u = ((unsigned)h) << 16;
    return v.f;
}

DEVINL bf16x8 cvt8(float4 lo, float4 hi) {
    bf16x8 r;
    r[0] = (short)f2bf(lo.x); r[1] = (short)f2bf(lo.y);
    r[2] = (short)f2bf(lo.z); r[3] = (short)f2bf(lo.w);
    r[4] = (short)f2bf(hi.x); r[5] = (short)f2bf(hi.y);
    r[6] = (short)f2bf(hi.z); r[7] = (short)f2bf(hi.w);
    return r;
}

constexpr int BM = 32, BN = 256, BK = 32;
constexpr int NSP = 256;                 // H*W
constexpr int SLICE = 64 * 32;           // one sB buffer per wave (u16)

// ---------------------------------------------------------------------------
// Transpose + bf16 convert: x[b][2048][256] f32 -> xT[b][256][2048] bf16.
__global__ __launch_bounds__(256)
void xpose(const float* __restrict__ x, unsigned short* __restrict__ xT)
{
    __shared__ float sh[64][65];
    const int b   = blockIdx.y;
    const int kt  = blockIdx.x & 31;     // 2048/64
    const int ntb = blockIdx.x >> 5;     // 256/64
    const int k0 = kt * 64, n0 = ntb * 64;

    const int r = threadIdx.x >> 4;          // 0..15
    const int c = (threadIdx.x & 15) * 4;    // 0..60

    const float* xb = x + ((size_t)b * 2048 + k0) * 256 + n0;
#pragma unroll
    for (int i = 0; i < 4; ++i) {
        float4 v = *(const float4*)(xb + (size_t)(r + 16 * i) * 256 + c);
        sh[r + 16 * i][c + 0] = v.x;
        sh[r + 16 * i][c + 1] = v.y;
        sh[r + 16 * i][c + 2] = v.z;
        sh[r + 16 * i][c + 3] = v.w;
    }
    __syncthreads();
#pragma unroll
    for (int i = 0; i < 4; ++i) {
        const int rr = r + 16 * i;           // n within tile
        ushort4 o;
        o.x = f2bf(sh[c + 0][rr]);
        o.y = f2bf(sh[c + 1][rr]);
        o.z = f2bf(sh[c + 2][rr]);
        o.w = f2bf(sh[c + 3][rr]);
        *(ushort4*)(xT + ((size_t)b * NSP + n0 + rr) * 2048 + k0 + c) = o;
    }
}

// ---------------------------------------------------------------------------
// Y^T[b][n][m] = sigmoid( sum_k W[b][m][k]*XT[b][n][k] + bias[b][m] ), bf16 out.
// BARRIER-FREE K-loop: every LDS byte is wave-private.
//  - Block = 32x256 output; 4 waves, each a PRIVATE 32x64 tile (wn = wid*64).
//  - B (xT/act): global_load_lds into the wave's private [2][64][32] slice
//    (slot-XOR swizzle via pre-swizzled global source; proven R7 involution).
//  - A (W f32): direct per-lane fragment loads (rows m0+mi*16+fr, 2 float4
//    per frag), cvt to bf16 in-register at use. Never touches LDS.
//  - Pacing: per-wave counted vmcnt ledger. Steady state: 8 in flight
//    (B(t+1):4 + A(t+1):4). Per step: issue B(t+2)+A(t+2) [8 ops], then
//    s_waitcnt vmcnt(8) drains exactly t+1's ops. vmcnt(0) only in the tail.
//  - lgkmcnt(0) before each GLOADB: this wave's ds_reads of buffer p are in
//    registers before the same-buffer overwrite can even issue.
__global__ __launch_bounds__(256, 4)
void fc_gemm(const float* __restrict__ Wt, const float* __restrict__ bias,
             const unsigned short* __restrict__ X, unsigned short* __restrict__ Yt,
             int M, int K)
{
    const int b  = blockIdx.x;               // linear id mod 8 = b mod 8 -> all
    const int m0 = blockIdx.y * BM;          // m-blocks of a sample on one XCD

    __shared__ __align__(128) unsigned short sB[4 * 2 * SLICE];   // 32 KiB

    const int tid  = threadIdx.x;
    const int lane = tid & 63;
    const int wid  = tid >> 6;               // 0..3
    const int wn   = wid * 64;               // wave's private n-offset
    const int fr   = lane & 15;
    const int fo8  = (lane >> 4) * 8;        // k-elem offset (elements)

    unsigned short* mySB = sB + wid * (2 * SLICE);   // wave-private 8 KiB

    // A: per-lane W rows (f32), frag mi -> row m0 + mi*16 + fr
    const float* wr0 = Wt + (size_t)b * M * K + (size_t)(m0 + fr) * K + fo8;
    const float* wr1 = wr0 + (size_t)16 * K;

    // B gload source (swizzled) / frag-read slot (involution)
    const int grow  = lane >> 2;                          // + i*16 rows in slice
    const int gchk  = ((lane & 3) ^ ((lane >> 3) & 3)) * 8;
    const int bslot = ((lane >> 4) ^ ((fr >> 1) & 3)) * 8;
    const unsigned short* Xb = X + ((size_t)b * NSP + wn) * K;

    const int NT = K / BK;                   // 64/32/16/8 (even)

    float4 aA[4], aB[4];                     // two named f32 A-sets (rule #20)

#define LOADA(SET, k0) { \
        SET[0] = *(const float4*)(wr0 + (k0));     \
        SET[1] = *(const float4*)(wr0 + (k0) + 4); \
        SET[2] = *(const float4*)(wr1 + (k0));     \
        SET[3] = *(const float4*)(wr1 + (k0) + 4); }
#define GLOADB(k0, p) { \
    _Pragma("unroll") for (int i = 0; i < 4; ++i) { \
        const unsigned short* src_ = Xb + (size_t)(grow + i * 16) * K + (k0) + gchk; \
        unsigned short* dst_ = mySB + (p) * SLICE + (i * 16) * 32; \
        __builtin_amdgcn_global_load_lds( \
            (const __attribute__((address_space(1))) void*)src_, \
            (__attribute__((address_space(3))) void*)dst_, 16, 0, 0); } }

    f32x4 acc[2][4] = {};

    // Prologue: issue tiles 0 and 1 (16 vmem); wait vmcnt(8) -> tile 0 landed.
    GLOADB(0, 0)
    LOADA(aA, 0)
    GLOADB(BK, 1)
    LOADA(aB, BK)
    asm volatile("s_waitcnt vmcnt(8)" ::: "memory");

    // Invariant at top of step t: B(t) in mySB[t&1] (landed), A(t) in SET
    // (landed), B(t+1)+A(t+1) in flight (8 ops).
#define KSTEP(t_, SET) { \
    const int tt = (t_); const int p = tt & 1; \
    bf16x8 af0 = cvt8(SET[0], SET[1]); \
    bf16x8 af1 = cvt8(SET[2], SET[3]); \
    bf16x8 bfv[4]; \
    _Pragma("unroll") for (int i = 0; i < 4; ++i) \
        bfv[i] = *(const bf16x8*)&mySB[p * SLICE + (i * 16 + fr) * 32 + bslot]; \
    _Pragma("unroll") for (int ni = 0; ni < 4; ++ni) { \
        acc[0][ni] = __builtin_amdgcn_mfma_f32_16x16x32_bf16(af0, bfv[ni], acc[0][ni], 0, 0, 0); \
        acc[1][ni] = __builtin_amdgcn_mfma_f32_16x16x32_bf16(af1, bfv[ni], acc[1][ni], 0, 0, 0); } \
    asm volatile("s_waitcnt lgkmcnt(0)" ::: "memory");  /* reads of buf p done */ \
    if (tt + 2 < NT) { \
        GLOADB((tt + 2) * BK, p)      /* overwrite buf p (safe: reads drained) */ \
        LOADA(SET, (tt + 2) * BK)     /* refill this set */ \
        asm volatile("s_waitcnt vmcnt(8)" ::: "memory");  /* t+1 landed */ \
    } else { \
        asm volatile("s_waitcnt vmcnt(0)" ::: "memory");  /* tail drain */ \
    } }

#pragma unroll 1
    for (int t = 0; t < NT; t += 2) {
        KSTEP(t,     aA)
        KSTEP(t + 1, aB)
    }
#undef KSTEP
#undef LOADA
#undef GLOADB

    // ---- Epilogue: bias + sigmoid + pack, direct scatter stores (no LDS,
    // no barriers; L2/L3 absorb partial lines — R4-verified).
    const int hi4 = (lane >> 4) * 4;
#pragma unroll
    for (int mi = 0; mi < 2; ++mi) {
#pragma unroll
        for (int ni = 0; ni < 4; ++ni) {
            const int n  = wn + ni * 16 + fr;
            const int mb = m0 + mi * 16 + hi4;
            f32x4 v = acc[mi][ni];
            ushort4 o;
#pragma unroll
            for (int q = 0; q < 4; ++q) {
                float yv = v[q] + bias[(size_t)b * M + mb + q];
                yv = 1.0f / (1.0f + __expf(-yv));
                ((unsigned short*)&o)[q] = f2bf(yv);
            }
            *(ushort4*)&Yt[((size_t)b * NSP + n) * M + mb] = o;
        }
    }
}

// Layer 5: out[b][n] = sum_k act4T[b][n][k] * w5[b][k] + b5[b]   (no sigmoid)
__global__ void fc_final(const unsigned short* __restrict__ A4,
                         const float* __restrict__ W5,
                         const float* __restrict__ B5,
                         float* __restrict__ out)
{
    const int b = blockIdx.x;
    const int t = threadIdx.x;  // 0..255 spatial
    const unsigned short* row = A4 + ((size_t)b * NSP + t) * 128;
    const float* w = W5 + (size_t)b * 128;
    float acc = B5[b];
#pragma unroll
    for (int k = 0; k < 128; k += 8) {
        uint4 v = *(const uint4*)(row + k);
        acc += bf2f((unsigned short)(v.x & 0xffff)) * w[k+0];
        acc += bf2f((unsigned short)(v.x >> 16))    * w[k+1];
        acc += bf2f((unsigned short)(v.y & 0xffff)) * w[k+2];
        acc += bf2f((unsigned short)(v.y >> 16))    * w[k+3];
        acc += bf2f((unsigned short)(v.z & 0xffff)) * w[k+4];
        acc += bf2f((unsigned short)(v.z >> 16))    * w[k+5];
        acc += bf2f((unsigned short)(v.w & 0xffff)) * w[k+6];
        acc += bf2f((unsigned short)(v.w >> 16))    * w[k+7];
    }
    out[b * NSP + t] = acc;
}

extern "C" void kernel_launch(void* const* d_in, const int* in_sizes, int n_in,
                              void* d_out, int out_size, void* d_ws, size_t ws_size,
                              hipStream_t stream)
{
    const float* x  = (const float*)d_in[0];
    const float* w1 = (const float*)d_in[1];
    const float* b1 = (const float*)d_in[2];
    const float* w2 = (const float*)d_in[3];
    const float* b2 = (const float*)d_in[4];
    const float* w3 = (const float*)d_in[5];
    const float* b3 = (const float*)d_in[6];
    const float* w4 = (const float*)d_in[7];
    const float* b4 = (const float*)d_in[8];
    const float* w5 = (const float*)d_in[9];
    const float* b5 = (const float*)d_in[10];

    unsigned short* ws0 = (unsigned short*)d_ws;

    // u16-element offsets. xT dead after L1 -> act2/3/4 reuse its region.
    const size_t XT = (size_t)64 * 256 * 2048;  // 33.55M u16 (67.1 MB)
    unsigned short* xT   = ws0;
    unsigned short* act1 = ws0 + XT;
    unsigned short* act2 = ws0;
    unsigned short* act3 = ws0 + (size_t)64 * 256 * 512;
    unsigned short* act4 = ws0 + (size_t)64 * 256 * (512 + 256);

    xpose<<<dim3(128, 64), dim3(256), 0, stream>>>(x, xT);
    fc_gemm<<<dim3(64, 32), dim3(256), 0, stream>>>(w1, b1, xT,   act1, 1024, 2048);
    fc_gemm<<<dim3(64, 16), dim3(256), 0, stream>>>(w2, b2, act1, act2,  512, 1024);
    fc_gemm<<<dim3(64,  8), dim3(256), 0, stream>>>(w3, b3, act2, act3,  256,  512);
    fc_gemm<<<dim3(64,  4), dim3(256), 0, stream>>>(w4, b4, act3, act4,  128,  256);
    fc_final<<<dim3(64), dim3(256), 0, stream>>>(act4, w5, b5, (float*)d_out);
}

// Round 14
// 387.972 us; speedup vs baseline: 1.5412x; 1.5412x over previous
//
#include <hip/hip_runtime.h>
#include <hip/hip_bf16.h>
#include <cstdint>

#define DEVINL __device__ __forceinline__

typedef __attribute__((ext_vector_type(8))) short bf16x8;
typedef __attribute__((ext_vector_type(4))) float f32x4;

DEVINL unsigned short f2bf(float f) {
    union { float f; unsigned u; } v; v.f = f;
    unsigned r = v.u + 0x7fffu + ((v.u >> 16) & 1u);   // RNE
    return (unsigned short)(r >> 16);
}
DEVINL float bf2f(unsigned short h) {
    union { unsigned u; float f; } v; v.u = ((unsigned)h) << 16;
    return v.f;
}

constexpr int BM = 64, BN = 256, BK = 32;
constexpr int NSP   = 256;        // H*W
constexpr int SABUF = 64 * 32;    // one sA buffer (u16)
constexpr int SBUF  = 256 * 32;   // one sB buffer (u16)

// ---------------------------------------------------------------------------
// Transpose + bf16 convert: x[b][2048][256] f32 -> xT[b][256][2048] bf16.
__global__ __launch_bounds__(256)
void xpose(const float* __restrict__ x, unsigned short* __restrict__ xT)
{
    __shared__ float sh[64][65];
    const int b   = blockIdx.y;
    const int kt  = blockIdx.x & 31;     // 2048/64
    const int ntb = blockIdx.x >> 5;     // 256/64
    const int k0 = kt * 64, n0 = ntb * 64;

    const int r = threadIdx.x >> 4;          // 0..15
    const int c = (threadIdx.x & 15) * 4;    // 0..60

    const float* xb = x + ((size_t)b * 2048 + k0) * 256 + n0;
#pragma unroll
    for (int i = 0; i < 4; ++i) {
        float4 v = *(const float4*)(xb + (size_t)(r + 16 * i) * 256 + c);
        sh[r + 16 * i][c + 0] = v.x;
        sh[r + 16 * i][c + 1] = v.y;
        sh[r + 16 * i][c + 2] = v.z;
        sh[r + 16 * i][c + 3] = v.w;
    }
    __syncthreads();
#pragma unroll
    for (int i = 0; i < 4; ++i) {
        const int rr = r + 16 * i;           // n within tile
        ushort4 o;
        o.x = f2bf(sh[c + 0][rr]);
        o.y = f2bf(sh[c + 1][rr]);
        o.z = f2bf(sh[c + 2][rr]);
        o.w = f2bf(sh[c + 3][rr]);
        *(ushort4*)(xT + ((size_t)b * NSP + n0 + rr) * 2048 + k0 + c) = o;
    }
}

// ---------------------------------------------------------------------------
// Y^T[b][n][m] = sigmoid( sum_k W[b][m][k]*XT[b][n][k] + bias[b][m] ), bf16 out.
// R10's proven structure with 8 WAVES (512 thr): wave grid 1x8 over the 64x256
// block tile (wave tile 64x32; af[4] x bfv[2], acc 4x2). LDS layout unchanged
// (40,960 B -> 4 blocks/CU), so occupancy doubles: 32 waves/CU (was 16).
//   - sA dbuf linear [2][64][32]; A staged 1 float4/thread (coalesced).
//   - B via global_load_lds, slot-XOR swizzle (R13-verified 0 bank conflicts);
//     each wave loads/reads only its private rows [wid*32, wid*32+32).
//   - ONE __syncthreads per K-step (protects shared sA); LOADA/GLOADB at step
//     top, STOREA after MFMA (issue-early/store-late); compiler waits only.
__global__ __launch_bounds__(512, 8)
void fc_gemm(const float* __restrict__ Wt, const float* __restrict__ bias,
             const unsigned short* __restrict__ X, unsigned short* __restrict__ Yt,
             int M, int K)
{
    const int b  = blockIdx.x;
    const int m0 = blockIdx.y * BM;

    // pool: 2 x sA (2048 u16) + 2 x sB (8192 u16) = 40960 B.
    // Epilogue reuses pool as [128][72] u16 (18432 B).
    __shared__ __align__(128) unsigned short pool[2 * SABUF + 2 * SBUF];
    unsigned short* sA = pool;
    unsigned short* sB = pool + 2 * SABUF;

    const int tid  = threadIdx.x;
    const int lane = tid & 63;
    const int wid  = tid >> 6;            // 0..7
    const int wn   = wid * 32;            // wave's private n-offset
    const int fr   = lane & 15;
    const int fo   = (lane >> 4) * 8;     // k-chunk offset (u16)

    // A staging: 64x32 f32, thread owns row tid>>3, one float4 at (tid&7)*4
    const int am = tid >> 3, ac = (tid & 7) * 4;
    const float* Wb = Wt + (size_t)b * M * K + (size_t)m0 * K + (size_t)am * K + ac;

    // B gload source: wave wid covers rows [wid*32, wid*32+32), 2 ops x 16 rows
    const int grow = wid * 32 + (lane >> 2);                 // + i*16
    const int gchk = ((lane & 3) ^ ((lane >> 3) & 3)) * 8;   // elem offset in row
    const unsigned short* Xb = X + (size_t)b * NSP * K;

    // B frag read slot (involution of the write swizzle; 0-conflict verified)
    const int bslot = ((lane >> 4) ^ ((fr >> 1) & 3)) * 8;

    const int NT = K / BK;   // 64/32/16/8

    float4 aS;               // single A staging value (issue-early / store-late)

#define LOADA(k0) { aS = *(const float4*)(Wb + (k0)); }
#define STOREA(p) { uint2 w_; \
        w_.x = (unsigned)f2bf(aS.x) | ((unsigned)f2bf(aS.y) << 16); \
        w_.y = (unsigned)f2bf(aS.z) | ((unsigned)f2bf(aS.w) << 16); \
        *(uint2*)&sA[(p) * SABUF + am * 32 + ac] = w_; }
#define GLOADB(k0, p) { \
    _Pragma("unroll") for (int i = 0; i < 2; ++i) { \
        const unsigned short* src_ = Xb + (size_t)(grow + i * 16) * K + (k0) + gchk; \
        const unsigned short* dst_ = sB + (p) * SBUF + (wid * 32 + i * 16) * 32; \
        __builtin_amdgcn_global_load_lds( \
            (const __attribute__((address_space(1))) void*)src_, \
            (__attribute__((address_space(3))) void*)dst_, 16, 0, 0); } }

    f32x4 acc[4][2] = {};

    // Prologue: B(0) + A(0) -> buffers 0; single drain.
    GLOADB(0, 0)
    LOADA(0)
    STOREA(0)
    __syncthreads();

#pragma unroll 1
    for (int t = 0; t < NT; ++t) {
        const int p = t & 1;
        if (t + 1 < NT) { LOADA((t + 1) * BK) GLOADB((t + 1) * BK, p ^ 1) }

        bf16x8 af[4], bfv[2];
#pragma unroll
        for (int i = 0; i < 4; ++i)
            af[i] = *(const bf16x8*)&sA[p * SABUF + (i * 16 + fr) * 32 + fo];
#pragma unroll
        for (int i = 0; i < 2; ++i)
            bfv[i] = *(const bf16x8*)&sB[p * SBUF + (wn + i * 16 + fr) * 32 + bslot];

#pragma unroll
        for (int mi = 0; mi < 4; ++mi)
#pragma unroll
            for (int ni = 0; ni < 2; ++ni)
                acc[mi][ni] = __builtin_amdgcn_mfma_f32_16x16x32_bf16(af[mi], bfv[ni], acc[mi][ni], 0, 0, 0);

        if (t + 1 < NT) STOREA(p ^ 1)   // A(t+1) had ~full step of cover

        __syncthreads();                // single per-step barrier
    }
#undef LOADA
#undef STOREA
#undef GLOADB

    // ---- Epilogue: bias+sigmoid+pack -> LDS [128][72] -> 128B-contiguous rows.
    const int hi4 = (lane >> 4) * 4;
#pragma unroll 1
    for (int ph = 0; ph < 2; ++ph) {
        if ((wn >> 7) == ph) {
#pragma unroll
            for (int mi = 0; mi < 4; ++mi) {
#pragma unroll
                for (int ni = 0; ni < 2; ++ni) {
                    const int r  = (wn & 127) + ni * 16 + fr;   // n within phase
                    const int mb = mi * 16 + hi4;               // m within block
                    f32x4 v = acc[mi][ni];
                    ushort4 o;
#pragma unroll
                    for (int q = 0; q < 4; ++q) {
                        float yv = v[q] + bias[(size_t)b * M + m0 + mb + q];
                        yv = 1.0f / (1.0f + __expf(-yv));
                        ((unsigned short*)&o)[q] = f2bf(yv);
                    }
                    *(ushort4*)&pool[r * 72 + mb] = o;
                }
            }
        }
        __syncthreads();
        const int r = tid >> 3;             // 0..63
        const int c = (tid & 7) * 8;        // 0..56
#pragma unroll
        for (int it = 0; it < 2; ++it) {
            const int rr = r + it * 64;
            uint4 v = *(const uint4*)&pool[rr * 72 + c];
            *(uint4*)&Yt[((size_t)b * NSP + ph * 128 + rr) * M + m0 + c] = v;
        }
        __syncthreads();
    }
}

// Layer 5: out[b][n] = sum_k act4T[b][n][k] * w5[b][k] + b5[b]   (no sigmoid)
__global__ void fc_final(const unsigned short* __restrict__ A4,
                         const float* __restrict__ W5,
                         const float* __restrict__ B5,
                         float* __restrict__ out)
{
    const int b = blockIdx.x;
    const int t = threadIdx.x;  // 0..255 spatial
    const unsigned short* row = A4 + ((size_t)b * NSP + t) * 128;
    const float* w = W5 + (size_t)b * 128;
    float acc = B5[b];
#pragma unroll
    for (int k = 0; k < 128; k += 8) {
        uint4 v = *(const uint4*)(row + k);
        acc += bf2f((unsigned short)(v.x & 0xffff)) * w[k+0];
        acc += bf2f((unsigned short)(v.x >> 16))    * w[k+1];
        acc += bf2f((unsigned short)(v.y & 0xffff)) * w[k+2];
        acc += bf2f((unsigned short)(v.y >> 16))    * w[k+3];
        acc += bf2f((unsigned short)(v.z & 0xffff)) * w[k+4];
        acc += bf2f((unsigned short)(v.z >> 16))    * w[k+5];
        acc += bf2f((unsigned short)(v.w & 0xffff)) * w[k+6];
        acc += bf2f((unsigned short)(v.w >> 16))    * w[k+7];
    }
    out[b * NSP + t] = acc;
}

extern "C" void kernel_launch(void* const* d_in, const int* in_sizes, int n_in,
                              void* d_out, int out_size, void* d_ws, size_t ws_size,
                              hipStream_t stream)
{
    const float* x  = (const float*)d_in[0];
    const float* w1 = (const float*)d_in[1];
    const float* b1 = (const float*)d_in[2];
    const float* w2 = (const float*)d_in[3];
    const float* b2 = (const float*)d_in[4];
    const float* w3 = (const float*)d_in[5];
    const float* b3 = (const float*)d_in[6];
    const float* w4 = (const float*)d_in[7];
    const float* b4 = (const float*)d_in[8];
    const float* w5 = (const float*)d_in[9];
    const float* b5 = (const float*)d_in[10];

    unsigned short* ws0 = (unsigned short*)d_ws;

    // u16-element offsets. xT dead after L1 -> act2/3/4 reuse its region.
    const size_t XT = (size_t)64 * 256 * 2048;  // 33.55M u16 (67.1 MB)
    unsigned short* xT   = ws0;
    unsigned short* act1 = ws0 + XT;
    unsigned short* act2 = ws0;
    unsigned short* act3 = ws0 + (size_t)64 * 256 * 512;
    unsigned short* act4 = ws0 + (size_t)64 * 256 * (512 + 256);

    xpose<<<dim3(128, 64), dim3(256), 0, stream>>>(x, xT);
    fc_gemm<<<dim3(64, 16), dim3(512), 0, stream>>>(w1, b1, xT,   act1, 1024, 2048);
    fc_gemm<<<dim3(64,  8), dim3(512), 0, stream>>>(w2, b2, act1, act2,  512, 1024);
    fc_gemm<<<dim3(64,  4), dim3(512), 0, stream>>>(w3, b3, act2, act3,  256,  512);
    fc_gemm<<<dim3(64,  2), dim3(512), 0, stream>>>(w4, b4, act3, act4,  128,  256);
    fc_final<<<dim3(64), dim3(256), 0, stream>>>(act4, w5, b5, (float*)d_out);
}

// Round 15
// 345.811 us; speedup vs baseline: 1.7291x; 1.1219x over previous
//
#include <hip/hip_runtime.h>
#include <hip/hip_bf16.h>
#include <cstdint>

#define DEVINL __device__ __forceinline__

typedef __attribute__((ext_vector_type(8))) short bf16x8;
typedef __attribute__((ext_vector_type(4))) float f32x4;

// Native RNE f32->bf16 (compiler emits v_cvt_pk_bf16_f32 for pairs).
DEVINL unsigned short bfbits(float f) {
    union { __hip_bfloat16 h; unsigned short s; } v;
    v.h = __float2bfloat16(f);
    return v.s;
}
DEVINL unsigned pk2(float a, float b) {
    return (unsigned)bfbits(a) | ((unsigned)bfbits(b) << 16);
}
DEVINL float bf2f(unsigned short h) {
    union { unsigned u; float f; } v; v.u = ((unsigned)h) << 16;
    return v.f;
}

constexpr int BM = 64, BN = 256, BK = 32;
constexpr int NSP   = 256;        // H*W
constexpr int SABUF = 64 * 32;    // one sA buffer (u16)
constexpr int SBUF  = 256 * 32;   // one sB buffer (u16)

// ---------------------------------------------------------------------------
// Transpose + bf16 convert: x[b][2048][256] f32 -> xT[b][256][2048] bf16.
__global__ __launch_bounds__(256)
void xpose(const float* __restrict__ x, unsigned short* __restrict__ xT)
{
    __shared__ float sh[64][65];
    const int b   = blockIdx.y;
    const int kt  = blockIdx.x & 31;     // 2048/64
    const int ntb = blockIdx.x >> 5;     // 256/64
    const int k0 = kt * 64, n0 = ntb * 64;

    const int r = threadIdx.x >> 4;          // 0..15
    const int c = (threadIdx.x & 15) * 4;    // 0..60

    const float* xb = x + ((size_t)b * 2048 + k0) * 256 + n0;
#pragma unroll
    for (int i = 0; i < 4; ++i) {
        float4 v = *(const float4*)(xb + (size_t)(r + 16 * i) * 256 + c);
        sh[r + 16 * i][c + 0] = v.x;
        sh[r + 16 * i][c + 1] = v.y;
        sh[r + 16 * i][c + 2] = v.z;
        sh[r + 16 * i][c + 3] = v.w;
    }
    __syncthreads();
#pragma unroll
    for (int i = 0; i < 4; ++i) {
        const int rr = r + 16 * i;           // n within tile
        uint2 o;
        o.x = pk2(sh[c + 0][rr], sh[c + 1][rr]);
        o.y = pk2(sh[c + 2][rr], sh[c + 3][rr]);
        *(uint2*)(xT + ((size_t)b * NSP + n0 + rr) * 2048 + k0 + c) = o;
    }
}

// ---------------------------------------------------------------------------
// Y^T[b][n][m] = sigmoid( sum_k W[b][m][k]*XT[b][n][k] + bias[b][m] ), bf16 out.
// R10's proven structure (best: 357.7 us):
//   4 waves x 64x64 wave tiles over 64x256 block; BN=256 => W read once.
//   sA dbuf linear [2][64][32] (64B rows, uniform banks); A staged 1 float4/thr.
//   B via global_load_lds, slot-XOR swizzle (R13-verified 0 bank conflicts).
//   ONE __syncthreads per K-step; LOADA/GLOADB at step top, STOREA after MFMA
//   (issue-early/store-late); compiler-inserted waits ONLY.
// This round: native v_cvt_pk bf16 conversion (was 4-op integer RNE per elem)
// and direct-scatter epilogue (R13-verified; kills 4 barriers + LDS roundtrip).
__global__ __launch_bounds__(256, 4)
void fc_gemm(const float* __restrict__ Wt, const float* __restrict__ bias,
             const unsigned short* __restrict__ X, unsigned short* __restrict__ Yt,
             int M, int K)
{
    const int b  = blockIdx.x;
    const int m0 = blockIdx.y * BM;

    __shared__ __align__(128) unsigned short pool[2 * SABUF + 2 * SBUF];  // 40,960 B
    unsigned short* sA = pool;
    unsigned short* sB = pool + 2 * SABUF;

    const int tid  = threadIdx.x;
    const int lane = tid & 63;
    const int wid  = tid >> 6;            // 0..3
    const int wn   = wid * 64;            // wave's n-offset
    const int fr   = lane & 15;
    const int fo   = (lane >> 4) * 8;     // k-chunk offset (u16)

    // A staging: 64x32 f32, thread owns row tid>>2, one 16B chunk (tid&3)*8
    const int am = tid >> 2, ac = (tid & 3) * 8;
    const float* Wb = Wt + (size_t)b * M * K + (size_t)m0 * K + (size_t)am * K + ac;

    // B gload source: per-lane row/chunk with slot-XOR pre-swizzle (proven R7)
    const int grow = wid * 64 + (lane >> 2);                 // + i*16
    const int gchk = ((lane & 3) ^ ((lane >> 3) & 3)) * 8;   // elem offset in row
    const unsigned short* Xb = X + (size_t)b * NSP * K;

    // B frag read slot (involution of the write swizzle; 0-conflict verified)
    const int bslot = ((lane >> 4) ^ ((fr >> 1) & 3)) * 8;

    const int NT = K / BK;   // 64/32/16/8

    float4 aS0, aS1;         // single A staging set (issue-early / store-late)

#define LOADA(k0) { aS0 = *(const float4*)(Wb + (k0)); \
                    aS1 = *(const float4*)(Wb + (k0) + 4); }
#define STOREA(p) { uint4 w_; \
        w_.x = pk2(aS0.x, aS0.y); w_.y = pk2(aS0.z, aS0.w); \
        w_.z = pk2(aS1.x, aS1.y); w_.w = pk2(aS1.z, aS1.w); \
        *(uint4*)&sA[(p) * SABUF + am * 32 + ac] = w_; }
#define GLOADB(k0, p) { \
    _Pragma("unroll") for (int i = 0; i < 4; ++i) { \
        const unsigned short* src_ = Xb + (size_t)(grow + i * 16) * K + (k0) + gchk; \
        const unsigned short* dst_ = sB + (p) * SBUF + (wid * 64 + i * 16) * 32; \
        __builtin_amdgcn_global_load_lds( \
            (const __attribute__((address_space(1))) void*)src_, \
            (__attribute__((address_space(3))) void*)dst_, 16, 0, 0); } }

    f32x4 acc[4][4] = {};

    // Prologue: B(0) + A(0) -> buffers 0; single drain.
    GLOADB(0, 0)
    LOADA(0)
    STOREA(0)
    __syncthreads();

#pragma unroll 1
    for (int t = 0; t < NT; ++t) {
        const int p = t & 1;
        if (t + 1 < NT) { LOADA((t + 1) * BK) GLOADB((t + 1) * BK, p ^ 1) }

        bf16x8 af[4], bfv[4];
#pragma unroll
        for (int i = 0; i < 4; ++i)
            af[i] = *(const bf16x8*)&sA[p * SABUF + (i * 16 + fr) * 32 + fo];
#pragma unroll
        for (int i = 0; i < 4; ++i)
            bfv[i] = *(const bf16x8*)&sB[p * SBUF + (wn + i * 16 + fr) * 32 + bslot];

#pragma unroll
        for (int mi = 0; mi < 4; ++mi)
#pragma unroll
            for (int ni = 0; ni < 4; ++ni)
                acc[mi][ni] = __builtin_amdgcn_mfma_f32_16x16x32_bf16(af[mi], bfv[ni], acc[mi][ni], 0, 0, 0);

        if (t + 1 < NT) STOREA(p ^ 1)   // A(t+1) had ~full step of cover

        __syncthreads();                // single per-step barrier
    }
#undef LOADA
#undef STOREA
#undef GLOADB

    // ---- Epilogue: bias + sigmoid + pack, direct 8B fragment stores
    // (no LDS, no barriers; partial lines absorbed by L2/L3 — R4/R13 verified).
    const int hi4 = (lane >> 4) * 4;
#pragma unroll
    for (int mi = 0; mi < 4; ++mi) {
#pragma unroll
        for (int ni = 0; ni < 4; ++ni) {
            const int n  = wn + ni * 16 + fr;
            const int mb = m0 + mi * 16 + hi4;
            f32x4 v = acc[mi][ni];
            float y[4];
#pragma unroll
            for (int q = 0; q < 4; ++q) {
                float yv = v[q] + bias[(size_t)b * M + mb + q];
                y[q] = 1.0f / (1.0f + __expf(-yv));
            }
            uint2 o;
            o.x = pk2(y[0], y[1]);
            o.y = pk2(y[2], y[3]);
            *(uint2*)&Yt[((size_t)b * NSP + n) * M + mb] = o;
        }
    }
}

// Layer 5: out[b][n] = sum_k act4T[b][n][k] * w5[b][k] + b5[b]   (no sigmoid)
__global__ void fc_final(const unsigned short* __restrict__ A4,
                         const float* __restrict__ W5,
                         const float* __restrict__ B5,
                         float* __restrict__ out)
{
    const int b = blockIdx.x;
    const int t = threadIdx.x;  // 0..255 spatial
    const unsigned short* row = A4 + ((size_t)b * NSP + t) * 128;
    const float* w = W5 + (size_t)b * 128;
    float acc = B5[b];
#pragma unroll
    for (int k = 0; k < 128; k += 8) {
        uint4 v = *(const uint4*)(row + k);
        acc += bf2f((unsigned short)(v.x & 0xffff)) * w[k+0];
        acc += bf2f((unsigned short)(v.x >> 16))    * w[k+1];
        acc += bf2f((unsigned short)(v.y & 0xffff)) * w[k+2];
        acc += bf2f((unsigned short)(v.y >> 16))    * w[k+3];
        acc += bf2f((unsigned short)(v.z & 0xffff)) * w[k+4];
        acc += bf2f((unsigned short)(v.z >> 16))    * w[k+5];
        acc += bf2f((unsigned short)(v.w & 0xffff)) * w[k+6];
        acc += bf2f((unsigned short)(v.w >> 16))    * w[k+7];
    }
    out[b * NSP + t] = acc;
}

extern "C" void kernel_launch(void* const* d_in, const int* in_sizes, int n_in,
                              void* d_out, int out_size, void* d_ws, size_t ws_size,
                              hipStream_t stream)
{
    const float* x  = (const float*)d_in[0];
    const float* w1 = (const float*)d_in[1];
    const float* b1 = (const float*)d_in[2];
    const float* w2 = (const float*)d_in[3];
    const float* b2 = (const float*)d_in[4];
    const float* w3 = (const float*)d_in[5];
    const float* b3 = (const float*)d_in[6];
    const float* w4 = (const float*)d_in[7];
    const float* b4 = (const float*)d_in[8];
    const float* w5 = (const float*)d_in[9];
    const float* b5 = (const float*)d_in[10];

    unsigned short* ws0 = (unsigned short*)d_ws;

    // u16-element offsets. xT dead after L1 -> act2/3/4 reuse its region.
    const size_t XT = (size_t)64 * 256 * 2048;  // 33.55M u16 (67.1 MB)
    unsigned short* xT   = ws0;
    unsigned short* act1 = ws0 + XT;
    unsigned short* act2 = ws0;
    unsigned short* act3 = ws0 + (size_t)64 * 256 * 512;
    unsigned short* act4 = ws0 + (size_t)64 * 256 * (512 + 256);

    xpose<<<dim3(128, 64), dim3(256), 0, stream>>>(x, xT);
    fc_gemm<<<dim3(64, 16), dim3(256), 0, stream>>>(w1, b1, xT,   act1, 1024, 2048);
    fc_gemm<<<dim3(64,  8), dim3(256), 0, stream>>>(w2, b2, act1, act2,  512, 1024);
    fc_gemm<<<dim3(64,  4), dim3(256), 0, stream>>>(w3, b3, act2, act3,  256,  512);
    fc_gemm<<<dim3(64,  2), dim3(256), 0, stream>>>(w4, b4, act3, act4,  128,  256);
    fc_final<<<dim3(64), dim3(256), 0, stream>>>(act4, w5, b5, (float*)d_out);
}

// Round 16
// 308.890 us; speedup vs baseline: 1.9358x; 1.1195x over previous
//
#include <hip/hip_runtime.h>
#include <hip/hip_bf16.h>
#include <cstdint>

#define DEVINL __device__ __forceinline__

typedef __attribute__((ext_vector_type(8))) short bf16x8;
typedef __attribute__((ext_vector_type(4))) float f32x4;

// Native RNE f32->bf16 (compiler emits v_cvt_pk_bf16_f32 for pairs).
DEVINL unsigned short bfbits(float f) {
    union { __hip_bfloat16 h; unsigned short s; } v;
    v.h = __float2bfloat16(f);
    return v.s;
}
DEVINL unsigned pk2(float a, float b) {
    return (unsigned)bfbits(a) | ((unsigned)bfbits(b) << 16);
}
DEVINL float bf2f(unsigned short h) {
    union { unsigned u; float f; } v; v.u = ((unsigned)h) << 16;
    return v.f;
}

constexpr int BN = 256, BK = 32;
constexpr int NSP  = 256;         // H*W
constexpr int SBUF = 256 * 32;    // one sB buffer (u16)

// ---------------------------------------------------------------------------
// Transpose + bf16 convert: x[b][2048][256] f32 -> xT[b][256][2048] bf16.
__global__ __launch_bounds__(256)
void xpose(const float* __restrict__ x, unsigned short* __restrict__ xT)
{
    __shared__ float sh[64][65];
    const int b   = blockIdx.y;
    const int kt  = blockIdx.x & 31;     // 2048/64
    const int ntb = blockIdx.x >> 5;     // 256/64
    const int k0 = kt * 64, n0 = ntb * 64;

    const int r = threadIdx.x >> 4;          // 0..15
    const int c = (threadIdx.x & 15) * 4;    // 0..60

    const float* xb = x + ((size_t)b * 2048 + k0) * 256 + n0;
#pragma unroll
    for (int i = 0; i < 4; ++i) {
        float4 v = *(const float4*)(xb + (size_t)(r + 16 * i) * 256 + c);
        sh[r + 16 * i][c + 0] = v.x;
        sh[r + 16 * i][c + 1] = v.y;
        sh[r + 16 * i][c + 2] = v.z;
        sh[r + 16 * i][c + 3] = v.w;
    }
    __syncthreads();
#pragma unroll
    for (int i = 0; i < 4; ++i) {
        const int rr = r + 16 * i;           // n within tile
        uint2 o;
        o.x = pk2(sh[c + 0][rr], sh[c + 1][rr]);
        o.y = pk2(sh[c + 2][rr], sh[c + 3][rr]);
        *(uint2*)(xT + ((size_t)b * NSP + n0 + rr) * 2048 + k0 + c) = o;
    }
}

// ---------------------------------------------------------------------------
// L1 kernel: BM=128, 512 threads (8 waves, 2x4 grid of 64x64 wave tiles).
// R15's proven schedule: sA dbuf [2][128][32], sB dbuf [2][256][32] slot-XOR,
// ONE __syncthreads per K-step, LOADA/GLOADB at step top, STOREA after MFMA,
// native cvt_pk, direct-scatter epilogue. Halves B re-read traffic vs BM=64
// (8 m-blocks instead of 16 stream xT) at identical occupancy (16 waves/CU).
__global__ __launch_bounds__(512, 2)
void fc_gemm128(const float* __restrict__ Wt, const float* __restrict__ bias,
                const unsigned short* __restrict__ X, unsigned short* __restrict__ Yt,
                int M, int K)
{
    constexpr int BM    = 128;
    constexpr int SABUF = BM * 32;   // 4096 u16

    const int b  = blockIdx.x;
    const int m0 = blockIdx.y * BM;

    __shared__ __align__(128) unsigned short pool[2 * SABUF + 2 * SBUF];  // 49,152 B
    unsigned short* sA = pool;
    unsigned short* sB = pool + 2 * SABUF;

    const int tid  = threadIdx.x;
    const int lane = tid & 63;
    const int wid  = tid >> 6;            // 0..7
    const int wm   = (wid >> 2) * 64;     // wave m-offset (0 or 64)
    const int wn   = (wid & 3) * 64;      // wave n-offset
    const int fr   = lane & 15;
    const int fo   = (lane >> 4) * 8;     // k-chunk offset (u16)

    // A staging: 128x32 f32, thread owns row tid>>2, two float4 at (tid&3)*8
    const int am = tid >> 2, ac = (tid & 3) * 8;
    const float* Wb = Wt + (size_t)b * M * K + (size_t)m0 * K + (size_t)am * K + ac;

    // B gload: wave wid covers rows [wid*32, wid*32+32), 2 ops x 16 rows
    const int grow = wid * 32 + (lane >> 2);
    const int gchk = ((lane & 3) ^ ((lane >> 3) & 3)) * 8;
    const unsigned short* Xb = X + (size_t)b * NSP * K;

    const int bslot = ((lane >> 4) ^ ((fr >> 1) & 3)) * 8;

    const int NT = K / BK;

    float4 aS0, aS1;

#define LOADA(k0) { aS0 = *(const float4*)(Wb + (k0)); \
                    aS1 = *(const float4*)(Wb + (k0) + 4); }
#define STOREA(p) { uint4 w_; \
        w_.x = pk2(aS0.x, aS0.y); w_.y = pk2(aS0.z, aS0.w); \
        w_.z = pk2(aS1.x, aS1.y); w_.w = pk2(aS1.z, aS1.w); \
        *(uint4*)&sA[(p) * SABUF + am * 32 + ac] = w_; }
#define GLOADB(k0, p) { \
    _Pragma("unroll") for (int i = 0; i < 2; ++i) { \
        const unsigned short* src_ = Xb + (size_t)(grow + i * 16) * K + (k0) + gchk; \
        const unsigned short* dst_ = sB + (p) * SBUF + (wid * 32 + i * 16) * 32; \
        __builtin_amdgcn_global_load_lds( \
            (const __attribute__((address_space(1))) void*)src_, \
            (__attribute__((address_space(3))) void*)dst_, 16, 0, 0); } }

    f32x4 acc[4][4] = {};

    GLOADB(0, 0)
    LOADA(0)
    STOREA(0)
    __syncthreads();

#pragma unroll 1
    for (int t = 0; t < NT; ++t) {
        const int p = t & 1;
        if (t + 1 < NT) { LOADA((t + 1) * BK) GLOADB((t + 1) * BK, p ^ 1) }

        bf16x8 af[4], bfv[4];
#pragma unroll
        for (int i = 0; i < 4; ++i)
            af[i] = *(const bf16x8*)&sA[p * SABUF + (wm + i * 16 + fr) * 32 + fo];
#pragma unroll
        for (int i = 0; i < 4; ++i)
            bfv[i] = *(const bf16x8*)&sB[p * SBUF + (wn + i * 16 + fr) * 32 + bslot];

#pragma unroll
        for (int mi = 0; mi < 4; ++mi)
#pragma unroll
            for (int ni = 0; ni < 4; ++ni)
                acc[mi][ni] = __builtin_amdgcn_mfma_f32_16x16x32_bf16(af[mi], bfv[ni], acc[mi][ni], 0, 0, 0);

        if (t + 1 < NT) STOREA(p ^ 1)

        __syncthreads();
    }
#undef LOADA
#undef STOREA
#undef GLOADB

    // Direct-scatter epilogue (R15-proven).
    const int hi4 = (lane >> 4) * 4;
#pragma unroll
    for (int mi = 0; mi < 4; ++mi) {
#pragma unroll
        for (int ni = 0; ni < 4; ++ni) {
            const int n  = wn + ni * 16 + fr;
            const int mb = m0 + wm + mi * 16 + hi4;
            f32x4 v = acc[mi][ni];
            float y[4];
#pragma unroll
            for (int q = 0; q < 4; ++q) {
                float yv = v[q] + bias[(size_t)b * M + mb + q];
                y[q] = 1.0f / (1.0f + __expf(-yv));
            }
            uint2 o;
            o.x = pk2(y[0], y[1]);
            o.y = pk2(y[2], y[3]);
            *(uint2*)&Yt[((size_t)b * NSP + n) * M + mb] = o;
        }
    }
}

// ---------------------------------------------------------------------------
// Tail kernel: R15 verbatim (BM=64, 256 thr, 4 waves x 64x64; proven 345.8).
__global__ __launch_bounds__(256, 4)
void fc_gemm(const float* __restrict__ Wt, const float* __restrict__ bias,
             const unsigned short* __restrict__ X, unsigned short* __restrict__ Yt,
             int M, int K)
{
    constexpr int BM    = 64;
    constexpr int SABUF = BM * 32;

    const int b  = blockIdx.x;
    const int m0 = blockIdx.y * BM;

    __shared__ __align__(128) unsigned short pool[2 * SABUF + 2 * SBUF];  // 40,960 B
    unsigned short* sA = pool;
    unsigned short* sB = pool + 2 * SABUF;

    const int tid  = threadIdx.x;
    const int lane = tid & 63;
    const int wid  = tid >> 6;            // 0..3
    const int wn   = wid * 64;
    const int fr   = lane & 15;
    const int fo   = (lane >> 4) * 8;

    const int am = tid >> 2, ac = (tid & 3) * 8;
    const float* Wb = Wt + (size_t)b * M * K + (size_t)m0 * K + (size_t)am * K + ac;

    const int grow = wid * 64 + (lane >> 2);
    const int gchk = ((lane & 3) ^ ((lane >> 3) & 3)) * 8;
    const unsigned short* Xb = X + (size_t)b * NSP * K;

    const int bslot = ((lane >> 4) ^ ((fr >> 1) & 3)) * 8;

    const int NT = K / BK;

    float4 aS0, aS1;

#define LOADA(k0) { aS0 = *(const float4*)(Wb + (k0)); \
                    aS1 = *(const float4*)(Wb + (k0) + 4); }
#define STOREA(p) { uint4 w_; \
        w_.x = pk2(aS0.x, aS0.y); w_.y = pk2(aS0.z, aS0.w); \
        w_.z = pk2(aS1.x, aS1.y); w_.w = pk2(aS1.z, aS1.w); \
        *(uint4*)&sA[(p) * SABUF + am * 32 + ac] = w_; }
#define GLOADB(k0, p) { \
    _Pragma("unroll") for (int i = 0; i < 4; ++i) { \
        const unsigned short* src_ = Xb + (size_t)(grow + i * 16) * K + (k0) + gchk; \
        const unsigned short* dst_ = sB + (p) * SBUF + (wid * 64 + i * 16) * 32; \
        __builtin_amdgcn_global_load_lds( \
            (const __attribute__((address_space(1))) void*)src_, \
            (__attribute__((address_space(3))) void*)dst_, 16, 0, 0); } }

    f32x4 acc[4][4] = {};

    GLOADB(0, 0)
    LOADA(0)
    STOREA(0)
    __syncthreads();

#pragma unroll 1
    for (int t = 0; t < NT; ++t) {
        const int p = t & 1;
        if (t + 1 < NT) { LOADA((t + 1) * BK) GLOADB((t + 1) * BK, p ^ 1) }

        bf16x8 af[4], bfv[4];
#pragma unroll
        for (int i = 0; i < 4; ++i)
            af[i] = *(const bf16x8*)&sA[p * SABUF + (i * 16 + fr) * 32 + fo];
#pragma unroll
        for (int i = 0; i < 4; ++i)
            bfv[i] = *(const bf16x8*)&sB[p * SBUF + (wn + i * 16 + fr) * 32 + bslot];

#pragma unroll
        for (int mi = 0; mi < 4; ++mi)
#pragma unroll
            for (int ni = 0; ni < 4; ++ni)
                acc[mi][ni] = __builtin_amdgcn_mfma_f32_16x16x32_bf16(af[mi], bfv[ni], acc[mi][ni], 0, 0, 0);

        if (t + 1 < NT) STOREA(p ^ 1)

        __syncthreads();
    }
#undef LOADA
#undef STOREA
#undef GLOADB

    const int hi4 = (lane >> 4) * 4;
#pragma unroll
    for (int mi = 0; mi < 4; ++mi) {
#pragma unroll
        for (int ni = 0; ni < 4; ++ni) {
            const int n  = wn + ni * 16 + fr;
            const int mb = m0 + mi * 16 + hi4;
            f32x4 v = acc[mi][ni];
            float y[4];
#pragma unroll
            for (int q = 0; q < 4; ++q) {
                float yv = v[q] + bias[(size_t)b * M + mb + q];
                y[q] = 1.0f / (1.0f + __expf(-yv));
            }
            uint2 o;
            o.x = pk2(y[0], y[1]);
            o.y = pk2(y[2], y[3]);
            *(uint2*)&Yt[((size_t)b * NSP + n) * M + mb] = o;
        }
    }
}

// Layer 5: out[b][n] = sum_k act4T[b][n][k] * w5[b][k] + b5[b]   (no sigmoid)
__global__ void fc_final(const unsigned short* __restrict__ A4,
                         const float* __restrict__ W5,
                         const float* __restrict__ B5,
                         float* __restrict__ out)
{
    const int b = blockIdx.x;
    const int t = threadIdx.x;  // 0..255 spatial
    const unsigned short* row = A4 + ((size_t)b * NSP + t) * 128;
    const float* w = W5 + (size_t)b * 128;
    float acc = B5[b];
#pragma unroll
    for (int k = 0; k < 128; k += 8) {
        uint4 v = *(const uint4*)(row + k);
        acc += bf2f((unsigned short)(v.x & 0xffff)) * w[k+0];
        acc += bf2f((unsigned short)(v.x >> 16))    * w[k+1];
        acc += bf2f((unsigned short)(v.y & 0xffff)) * w[k+2];
        acc += bf2f((unsigned short)(v.y >> 16))    * w[k+3];
        acc += bf2f((unsigned short)(v.z & 0xffff)) * w[k+4];
        acc += bf2f((unsigned short)(v.z >> 16))    * w[k+5];
        acc += bf2f((unsigned short)(v.w & 0xffff)) * w[k+6];
        acc += bf2f((unsigned short)(v.w >> 16))    * w[k+7];
    }
    out[b * NSP + t] = acc;
}

extern "C" void kernel_launch(void* const* d_in, const int* in_sizes, int n_in,
                              void* d_out, int out_size, void* d_ws, size_t ws_size,
                              hipStream_t stream)
{
    const float* x  = (const float*)d_in[0];
    const float* w1 = (const float*)d_in[1];
    const float* b1 = (const float*)d_in[2];
    const float* w2 = (const float*)d_in[3];
    const float* b2 = (const float*)d_in[4];
    const float* w3 = (const float*)d_in[5];
    const float* b3 = (const float*)d_in[6];
    const float* w4 = (const float*)d_in[7];
    const float* b4 = (const float*)d_in[8];
    const float* w5 = (const float*)d_in[9];
    const float* b5 = (const float*)d_in[10];

    unsigned short* ws0 = (unsigned short*)d_ws;

    // u16-element offsets. xT dead after L1 -> act2/3/4 reuse its region.
    const size_t XT = (size_t)64 * 256 * 2048;  // 33.55M u16 (67.1 MB)
    unsigned short* xT   = ws0;
    unsigned short* act1 = ws0 + XT;
    unsigned short* act2 = ws0;
    unsigned short* act3 = ws0 + (size_t)64 * 256 * 512;
    unsigned short* act4 = ws0 + (size_t)64 * 256 * (512 + 256);

    xpose<<<dim3(128, 64), dim3(256), 0, stream>>>(x, xT);
    fc_gemm128<<<dim3(64, 8), dim3(512), 0, stream>>>(w1, b1, xT,   act1, 1024, 2048);
    fc_gemm<<<dim3(64,  8), dim3(256), 0, stream>>>(w2, b2, act1, act2,  512, 1024);
    fc_gemm<<<dim3(64,  4), dim3(256), 0, stream>>>(w3, b3, act2, act3,  256,  512);
    fc_gemm<<<dim3(64,  2), dim3(256), 0, stream>>>(w4, b4, act3, act4,  128,  256);
    fc_final<<<dim3(64), dim3(256), 0, stream>>>(act4, w5, b5, (float*)d_out);
}

// Round 17
// 300.432 us; speedup vs baseline: 1.9903x; 1.0282x over previous
//
#include <hip/hip_runtime.h>
#include <hip/hip_bf16.h>
#include <cstdint>

#define DEVINL __device__ __forceinline__

typedef __attribute__((ext_vector_type(8))) short bf16x8;
typedef __attribute__((ext_vector_type(4))) float f32x4;

// Native RNE f32->bf16 (compiler emits v_cvt_pk_bf16_f32 for pairs).
DEVINL unsigned short bfbits(float f) {
    union { __hip_bfloat16 h; unsigned short s; } v;
    v.h = __float2bfloat16(f);
    return v.s;
}
DEVINL unsigned pk2(float a, float b) {
    return (unsigned)bfbits(a) | ((unsigned)bfbits(b) << 16);
}
DEVINL float bf2f(unsigned short h) {
    union { unsigned u; float f; } v; v.u = ((unsigned)h) << 16;
    return v.f;
}

constexpr int BN = 256, BK = 32;
constexpr int NSP  = 256;         // H*W
constexpr int SBUF = 256 * 32;    // one sB buffer (u16)

// ---------------------------------------------------------------------------
// Transpose + bf16 convert: x[b][2048][256] f32 -> xT[b][256][2048] bf16.
__global__ __launch_bounds__(256)
void xpose(const float* __restrict__ x, unsigned short* __restrict__ xT)
{
    __shared__ float sh[64][65];
    const int b   = blockIdx.y;
    const int kt  = blockIdx.x & 31;     // 2048/64
    const int ntb = blockIdx.x >> 5;     // 256/64
    const int k0 = kt * 64, n0 = ntb * 64;

    const int r = threadIdx.x >> 4;          // 0..15
    const int c = (threadIdx.x & 15) * 4;    // 0..60

    const float* xb = x + ((size_t)b * 2048 + k0) * 256 + n0;
#pragma unroll
    for (int i = 0; i < 4; ++i) {
        float4 v = *(const float4*)(xb + (size_t)(r + 16 * i) * 256 + c);
        sh[r + 16 * i][c + 0] = v.x;
        sh[r + 16 * i][c + 1] = v.y;
        sh[r + 16 * i][c + 2] = v.z;
        sh[r + 16 * i][c + 3] = v.w;
    }
    __syncthreads();
#pragma unroll
    for (int i = 0; i < 4; ++i) {
        const int rr = r + 16 * i;           // n within tile
        uint2 o;
        o.x = pk2(sh[c + 0][rr], sh[c + 1][rr]);
        o.y = pk2(sh[c + 2][rr], sh[c + 3][rr]);
        *(uint2*)(xT + ((size_t)b * NSP + n0 + rr) * 2048 + k0 + c) = o;
    }
}

// ---------------------------------------------------------------------------
// L1 kernel: BM=256, 1024 threads (16 waves, 4x4 grid of 64x64 wave tiles).
// Same proven schedule: sA dbuf [2][256][32], sB dbuf [2][256][32] slot-XOR,
// ONE __syncthreads per K-step, LOADA/GLOADB at step top, STOREA after MFMA,
// native cvt_pk, direct-scatter epilogue. B re-read passes: 4 (was 8 at
// BM=128) -> L1 ideal traffic 838 MB. 1 block/CU, 16 waves/CU (same occ).
__global__ __launch_bounds__(1024, 1)
void fc_gemm256(const float* __restrict__ Wt, const float* __restrict__ bias,
                const unsigned short* __restrict__ X, unsigned short* __restrict__ Yt,
                int M, int K)
{
    constexpr int BM    = 256;
    constexpr int SABUF = BM * 32;   // 8192 u16

    const int b  = blockIdx.x;
    const int m0 = blockIdx.y * BM;

    __shared__ __align__(128) unsigned short pool[2 * SABUF + 2 * SBUF];  // 65,536 B
    unsigned short* sA = pool;
    unsigned short* sB = pool + 2 * SABUF;

    const int tid  = threadIdx.x;
    const int lane = tid & 63;
    const int wid  = tid >> 6;            // 0..15
    const int wm   = (wid >> 2) * 64;     // wave m-offset (0/64/128/192)
    const int wn   = (wid & 3) * 64;      // wave n-offset
    const int fr   = lane & 15;
    const int fo   = (lane >> 4) * 8;     // k-chunk offset (u16)

    // A staging: 256x32 f32, thread owns row tid>>2, two float4 at (tid&3)*8
    const int am = tid >> 2, ac = (tid & 3) * 8;
    const float* Wb = Wt + (size_t)b * M * K + (size_t)m0 * K + (size_t)am * K + ac;

    // B gload: wave wid covers rows [wid*16, wid*16+16), 1 op x 16 rows
    const int grow = wid * 16 + (lane >> 2);
    const int gchk = ((lane & 3) ^ ((lane >> 3) & 3)) * 8;
    const unsigned short* Xb = X + (size_t)b * NSP * K;

    const int bslot = ((lane >> 4) ^ ((fr >> 1) & 3)) * 8;

    const int NT = K / BK;

    float4 aS0, aS1;

#define LOADA(k0) { aS0 = *(const float4*)(Wb + (k0)); \
                    aS1 = *(const float4*)(Wb + (k0) + 4); }
#define STOREA(p) { uint4 w_; \
        w_.x = pk2(aS0.x, aS0.y); w_.y = pk2(aS0.z, aS0.w); \
        w_.z = pk2(aS1.x, aS1.y); w_.w = pk2(aS1.z, aS1.w); \
        *(uint4*)&sA[(p) * SABUF + am * 32 + ac] = w_; }
#define GLOADB(k0, p) { \
        const unsigned short* src_ = Xb + (size_t)grow * K + (k0) + gchk; \
        const unsigned short* dst_ = sB + (p) * SBUF + (wid * 16) * 32; \
        __builtin_amdgcn_global_load_lds( \
            (const __attribute__((address_space(1))) void*)src_, \
            (__attribute__((address_space(3))) void*)dst_, 16, 0, 0); }

    f32x4 acc[4][4] = {};

    GLOADB(0, 0)
    LOADA(0)
    STOREA(0)
    __syncthreads();

#pragma unroll 1
    for (int t = 0; t < NT; ++t) {
        const int p = t & 1;
        if (t + 1 < NT) { LOADA((t + 1) * BK) GLOADB((t + 1) * BK, p ^ 1) }

        bf16x8 af[4], bfv[4];
#pragma unroll
        for (int i = 0; i < 4; ++i)
            af[i] = *(const bf16x8*)&sA[p * SABUF + (wm + i * 16 + fr) * 32 + fo];
#pragma unroll
        for (int i = 0; i < 4; ++i)
            bfv[i] = *(const bf16x8*)&sB[p * SBUF + (wn + i * 16 + fr) * 32 + bslot];

#pragma unroll
        for (int mi = 0; mi < 4; ++mi)
#pragma unroll
            for (int ni = 0; ni < 4; ++ni)
                acc[mi][ni] = __builtin_amdgcn_mfma_f32_16x16x32_bf16(af[mi], bfv[ni], acc[mi][ni], 0, 0, 0);

        if (t + 1 < NT) STOREA(p ^ 1)

        __syncthreads();
    }
#undef LOADA
#undef STOREA
#undef GLOADB

    // Direct-scatter epilogue.
    const int hi4 = (lane >> 4) * 4;
#pragma unroll
    for (int mi = 0; mi < 4; ++mi) {
#pragma unroll
        for (int ni = 0; ni < 4; ++ni) {
            const int n  = wn + ni * 16 + fr;
            const int mb = m0 + wm + mi * 16 + hi4;
            f32x4 v = acc[mi][ni];
            float y[4];
#pragma unroll
            for (int q = 0; q < 4; ++q) {
                float yv = v[q] + bias[(size_t)b * M + mb + q];
                y[q] = 1.0f / (1.0f + __expf(-yv));
            }
            uint2 o;
            o.x = pk2(y[0], y[1]);
            o.y = pk2(y[2], y[3]);
            *(uint2*)&Yt[((size_t)b * NSP + n) * M + mb] = o;
        }
    }
}

// ---------------------------------------------------------------------------
// BM=128 kernel (R16-proven): 512 threads, 8 waves, 2x4 grid of 64x64 tiles.
__global__ __launch_bounds__(512, 2)
void fc_gemm128(const float* __restrict__ Wt, const float* __restrict__ bias,
                const unsigned short* __restrict__ X, unsigned short* __restrict__ Yt,
                int M, int K)
{
    constexpr int BM    = 128;
    constexpr int SABUF = BM * 32;   // 4096 u16

    const int b  = blockIdx.x;
    const int m0 = blockIdx.y * BM;

    __shared__ __align__(128) unsigned short pool[2 * SABUF + 2 * SBUF];  // 49,152 B
    unsigned short* sA = pool;
    unsigned short* sB = pool + 2 * SABUF;

    const int tid  = threadIdx.x;
    const int lane = tid & 63;
    const int wid  = tid >> 6;            // 0..7
    const int wm   = (wid >> 2) * 64;
    const int wn   = (wid & 3) * 64;
    const int fr   = lane & 15;
    const int fo   = (lane >> 4) * 8;

    const int am = tid >> 2, ac = (tid & 3) * 8;
    const float* Wb = Wt + (size_t)b * M * K + (size_t)m0 * K + (size_t)am * K + ac;

    const int grow = wid * 32 + (lane >> 2);
    const int gchk = ((lane & 3) ^ ((lane >> 3) & 3)) * 8;
    const unsigned short* Xb = X + (size_t)b * NSP * K;

    const int bslot = ((lane >> 4) ^ ((fr >> 1) & 3)) * 8;

    const int NT = K / BK;

    float4 aS0, aS1;

#define LOADA(k0) { aS0 = *(const float4*)(Wb + (k0)); \
                    aS1 = *(const float4*)(Wb + (k0) + 4); }
#define STOREA(p) { uint4 w_; \
        w_.x = pk2(aS0.x, aS0.y); w_.y = pk2(aS0.z, aS0.w); \
        w_.z = pk2(aS1.x, aS1.y); w_.w = pk2(aS1.z, aS1.w); \
        *(uint4*)&sA[(p) * SABUF + am * 32 + ac] = w_; }
#define GLOADB(k0, p) { \
    _Pragma("unroll") for (int i = 0; i < 2; ++i) { \
        const unsigned short* src_ = Xb + (size_t)(grow + i * 16) * K + (k0) + gchk; \
        const unsigned short* dst_ = sB + (p) * SBUF + (wid * 32 + i * 16) * 32; \
        __builtin_amdgcn_global_load_lds( \
            (const __attribute__((address_space(1))) void*)src_, \
            (__attribute__((address_space(3))) void*)dst_, 16, 0, 0); } }

    f32x4 acc[4][4] = {};

    GLOADB(0, 0)
    LOADA(0)
    STOREA(0)
    __syncthreads();

#pragma unroll 1
    for (int t = 0; t < NT; ++t) {
        const int p = t & 1;
        if (t + 1 < NT) { LOADA((t + 1) * BK) GLOADB((t + 1) * BK, p ^ 1) }

        bf16x8 af[4], bfv[4];
#pragma unroll
        for (int i = 0; i < 4; ++i)
            af[i] = *(const bf16x8*)&sA[p * SABUF + (wm + i * 16 + fr) * 32 + fo];
#pragma unroll
        for (int i = 0; i < 4; ++i)
            bfv[i] = *(const bf16x8*)&sB[p * SBUF + (wn + i * 16 + fr) * 32 + bslot];

#pragma unroll
        for (int mi = 0; mi < 4; ++mi)
#pragma unroll
            for (int ni = 0; ni < 4; ++ni)
                acc[mi][ni] = __builtin_amdgcn_mfma_f32_16x16x32_bf16(af[mi], bfv[ni], acc[mi][ni], 0, 0, 0);

        if (t + 1 < NT) STOREA(p ^ 1)

        __syncthreads();
    }
#undef LOADA
#undef STOREA
#undef GLOADB

    const int hi4 = (lane >> 4) * 4;
#pragma unroll
    for (int mi = 0; mi < 4; ++mi) {
#pragma unroll
        for (int ni = 0; ni < 4; ++ni) {
            const int n  = wn + ni * 16 + fr;
            const int mb = m0 + wm + mi * 16 + hi4;
            f32x4 v = acc[mi][ni];
            float y[4];
#pragma unroll
            for (int q = 0; q < 4; ++q) {
                float yv = v[q] + bias[(size_t)b * M + mb + q];
                y[q] = 1.0f / (1.0f + __expf(-yv));
            }
            uint2 o;
            o.x = pk2(y[0], y[1]);
            o.y = pk2(y[2], y[3]);
            *(uint2*)&Yt[((size_t)b * NSP + n) * M + mb] = o;
        }
    }
}

// ---------------------------------------------------------------------------
// Tail kernel: BM=64, 256 thr, 4 waves x 64x64 (R15-proven).
__global__ __launch_bounds__(256, 4)
void fc_gemm(const float* __restrict__ Wt, const float* __restrict__ bias,
             const unsigned short* __restrict__ X, unsigned short* __restrict__ Yt,
             int M, int K)
{
    constexpr int BM    = 64;
    constexpr int SABUF = BM * 32;

    const int b  = blockIdx.x;
    const int m0 = blockIdx.y * BM;

    __shared__ __align__(128) unsigned short pool[2 * SABUF + 2 * SBUF];  // 40,960 B
    unsigned short* sA = pool;
    unsigned short* sB = pool + 2 * SABUF;

    const int tid  = threadIdx.x;
    const int lane = tid & 63;
    const int wid  = tid >> 6;            // 0..3
    const int wn   = wid * 64;
    const int fr   = lane & 15;
    const int fo   = (lane >> 4) * 8;

    const int am = tid >> 2, ac = (tid & 3) * 8;
    const float* Wb = Wt + (size_t)b * M * K + (size_t)m0 * K + (size_t)am * K + ac;

    const int grow = wid * 64 + (lane >> 2);
    const int gchk = ((lane & 3) ^ ((lane >> 3) & 3)) * 8;
    const unsigned short* Xb = X + (size_t)b * NSP * K;

    const int bslot = ((lane >> 4) ^ ((fr >> 1) & 3)) * 8;

    const int NT = K / BK;

    float4 aS0, aS1;

#define LOADA(k0) { aS0 = *(const float4*)(Wb + (k0)); \
                    aS1 = *(const float4*)(Wb + (k0) + 4); }
#define STOREA(p) { uint4 w_; \
        w_.x = pk2(aS0.x, aS0.y); w_.y = pk2(aS0.z, aS0.w); \
        w_.z = pk2(aS1.x, aS1.y); w_.w = pk2(aS1.z, aS1.w); \
        *(uint4*)&sA[(p) * SABUF + am * 32 + ac] = w_; }
#define GLOADB(k0, p) { \
    _Pragma("unroll") for (int i = 0; i < 4; ++i) { \
        const unsigned short* src_ = Xb + (size_t)(grow + i * 16) * K + (k0) + gchk; \
        const unsigned short* dst_ = sB + (p) * SBUF + (wid * 64 + i * 16) * 32; \
        __builtin_amdgcn_global_load_lds( \
            (const __attribute__((address_space(1))) void*)src_, \
            (__attribute__((address_space(3))) void*)dst_, 16, 0, 0); } }

    f32x4 acc[4][4] = {};

    GLOADB(0, 0)
    LOADA(0)
    STOREA(0)
    __syncthreads();

#pragma unroll 1
    for (int t = 0; t < NT; ++t) {
        const int p = t & 1;
        if (t + 1 < NT) { LOADA((t + 1) * BK) GLOADB((t + 1) * BK, p ^ 1) }

        bf16x8 af[4], bfv[4];
#pragma unroll
        for (int i = 0; i < 4; ++i)
            af[i] = *(const bf16x8*)&sA[p * SABUF + (i * 16 + fr) * 32 + fo];
#pragma unroll
        for (int i = 0; i < 4; ++i)
            bfv[i] = *(const bf16x8*)&sB[p * SBUF + (wn + i * 16 + fr) * 32 + bslot];

#pragma unroll
        for (int mi = 0; mi < 4; ++mi)
#pragma unroll
            for (int ni = 0; ni < 4; ++ni)
                acc[mi][ni] = __builtin_amdgcn_mfma_f32_16x16x32_bf16(af[mi], bfv[ni], acc[mi][ni], 0, 0, 0);

        if (t + 1 < NT) STOREA(p ^ 1)

        __syncthreads();
    }
#undef LOADA
#undef STOREA
#undef GLOADB

    const int hi4 = (lane >> 4) * 4;
#pragma unroll
    for (int mi = 0; mi < 4; ++mi) {
#pragma unroll
        for (int ni = 0; ni < 4; ++ni) {
            const int n  = wn + ni * 16 + fr;
            const int mb = m0 + mi * 16 + hi4;
            f32x4 v = acc[mi][ni];
            float y[4];
#pragma unroll
            for (int q = 0; q < 4; ++q) {
                float yv = v[q] + bias[(size_t)b * M + mb + q];
                y[q] = 1.0f / (1.0f + __expf(-yv));
            }
            uint2 o;
            o.x = pk2(y[0], y[1]);
            o.y = pk2(y[2], y[3]);
            *(uint2*)&Yt[((size_t)b * NSP + n) * M + mb] = o;
        }
    }
}

// Layer 5: out[b][n] = sum_k act4T[b][n][k] * w5[b][k] + b5[b]   (no sigmoid)
__global__ void fc_final(const unsigned short* __restrict__ A4,
                         const float* __restrict__ W5,
                         const float* __restrict__ B5,
                         float* __restrict__ out)
{
    const int b = blockIdx.x;
    const int t = threadIdx.x;  // 0..255 spatial
    const unsigned short* row = A4 + ((size_t)b * NSP + t) * 128;
    const float* w = W5 + (size_t)b * 128;
    float acc = B5[b];
#pragma unroll
    for (int k = 0; k < 128; k += 8) {
        uint4 v = *(const uint4*)(row + k);
        acc += bf2f((unsigned short)(v.x & 0xffff)) * w[k+0];
        acc += bf2f((unsigned short)(v.x >> 16))    * w[k+1];
        acc += bf2f((unsigned short)(v.y & 0xffff)) * w[k+2];
        acc += bf2f((unsigned short)(v.y >> 16))    * w[k+3];
        acc += bf2f((unsigned short)(v.z & 0xffff)) * w[k+4];
        acc += bf2f((unsigned short)(v.z >> 16))    * w[k+5];
        acc += bf2f((unsigned short)(v.w & 0xffff)) * w[k+6];
        acc += bf2f((unsigned short)(v.w >> 16))    * w[k+7];
    }
    out[b * NSP + t] = acc;
}

extern "C" void kernel_launch(void* const* d_in, const int* in_sizes, int n_in,
                              void* d_out, int out_size, void* d_ws, size_t ws_size,
                              hipStream_t stream)
{
    const float* x  = (const float*)d_in[0];
    const float* w1 = (const float*)d_in[1];
    const float* b1 = (const float*)d_in[2];
    const float* w2 = (const float*)d_in[3];
    const float* b2 = (const float*)d_in[4];
    const float* w3 = (const float*)d_in[5];
    const float* b3 = (const float*)d_in[6];
    const float* w4 = (const float*)d_in[7];
    const float* b4 = (const float*)d_in[8];
    const float* w5 = (const float*)d_in[9];
    const float* b5 = (const float*)d_in[10];

    unsigned short* ws0 = (unsigned short*)d_ws;

    // u16-element offsets. xT dead after L1 -> act2/3/4 reuse its region.
    const size_t XT = (size_t)64 * 256 * 2048;  // 33.55M u16 (67.1 MB)
    unsigned short* xT   = ws0;
    unsigned short* act1 = ws0 + XT;
    unsigned short* act2 = ws0;
    unsigned short* act3 = ws0 + (size_t)64 * 256 * 512;
    unsigned short* act4 = ws0 + (size_t)64 * 256 * (512 + 256);

    xpose<<<dim3(128, 64), dim3(256), 0, stream>>>(x, xT);
    fc_gemm256<<<dim3(64, 4), dim3(1024), 0, stream>>>(w1, b1, xT,   act1, 1024, 2048);
    fc_gemm128<<<dim3(64, 4), dim3(512),  0, stream>>>(w2, b2, act1, act2,  512, 1024);
    fc_gemm<<<dim3(64, 4), dim3(256), 0, stream>>>(w3, b3, act2, act3,  256,  512);
    fc_gemm<<<dim3(64, 2), dim3(256), 0, stream>>>(w4, b4, act3, act4,  128,  256);
    fc_final<<<dim3(64), dim3(256), 0, stream>>>(act4, w5, b5, (float*)d_out);
}